// Round 5
// baseline (972.041 us; speedup 1.0000x reference)
//
#include <hip/hip_runtime.h>
#include <hip/hip_fp16.h>
#include <math.h>
#include <stdint.h>

#define B_   512
#define L_   128
#define K_   9
#define NE   50000
#define ZD   16
#define TE   32
#define XE   128
#define EP   8
#define H_   128
#define G4   512
#define OD   32
#define IN0  184
#define MKD  168

typedef uint32_t u32;
typedef _Float16 half2v __attribute__((ext_vector_type(2)));
typedef _Float16 half8  __attribute__((ext_vector_type(8)));
typedef float    f32x4  __attribute__((ext_vector_type(4)));

__device__ __forceinline__ float sigm(float x) {
    x = fminf(fmaxf(x, -30.f), 30.f);
    return 1.f / (1.f + expf(-x));
}
__device__ __forceinline__ float tanh_f(float x) {
    x = fminf(fmaxf(x, -15.f), 15.f);
    float e = expf(2.f * x);
    return (e - 1.f) / (e + 1.f);
}
__device__ __forceinline__ float dot2f(u32 w, u32 h, float acc) {
#if __has_builtin(__builtin_amdgcn_fdot2)
    union { u32 u; half2v v; } a, b;
    a.u = w; b.u = h;
    return __builtin_amdgcn_fdot2(a.v, b.v, acc, false);
#else
    union { u32 u; __half2 h2; } a, b;
    a.u = w; b.u = h;
    float2 fa = __half22float2(a.h2), fb = __half22float2(b.h2);
    return fmaf(fa.x, fb.x, fmaf(fa.y, fb.y, acc));
#endif
}
__device__ __forceinline__ float dot4(uint4 w, uint4 h, float acc) {
    acc = dot2f(w.x, h.x, acc); acc = dot2f(w.y, h.y, acc);
    acc = dot2f(w.z, h.z, acc); acc = dot2f(w.w, h.w, acc);
    return acc;
}
__device__ __forceinline__ u32 packh(float lo, float hi) {
    union { __half2 h; u32 u; } p;
    p.h = __halves2half2(__float2half(lo), __float2half(hi));
    return p.u;
}

// ---------------------------------------------------------------------------
// kW2: pack all weights (f16 pairs) + bias sums.  (layout: see round-4 notes)
// ---------------------------------------------------------------------------
__global__ void __launch_bounds__(256)
kW2(const float* __restrict__ w_ih0, const float* __restrict__ w_hh0,
    const float* __restrict__ w_ih1, const float* __restrict__ w_hh1,
    const float* __restrict__ w_ih2, const float* __restrict__ w_hh2,
    const float* __restrict__ wax, const float* __restrict__ wmx,
    const float* __restrict__ wmt, const float* __restrict__ wat,
    const float* __restrict__ b_ih0, const float* __restrict__ b_hh0,
    const float* __restrict__ b_ih1, const float* __restrict__ b_hh1,
    const float* __restrict__ b_ih2, const float* __restrict__ b_hh2,
    u32* __restrict__ wsu)
{
    int gid = blockIdx.x * 256 + threadIdx.x;
    if (gid < 49152) {
        int g = gid / 96, c = gid % 96;
        wsu[gid] = (c < 92) ? packh(w_ih0[g * IN0 + 2 * c], w_ih0[g * IN0 + 2 * c + 1]) : 0u;
    } else if (gid < 81920) {
        int e = gid - 49152; int g = e >> 6, c = e & 63;
        wsu[gid] = packh(w_hh0[g * H_ + 2 * c], w_hh0[g * H_ + 2 * c + 1]);
    } else if (gid < 114688) {
        int e = gid - 81920; int g = e >> 6, c = e & 63;
        wsu[gid] = packh(w_ih1[g * H_ + 2 * c], w_ih1[g * H_ + 2 * c + 1]);
    } else if (gid < 147456) {
        int e = gid - 114688; int g = e >> 6, c = e & 63;
        wsu[gid] = packh(w_hh1[g * H_ + 2 * c], w_hh1[g * H_ + 2 * c + 1]);
    } else if (gid < 180224) {
        int e = gid - 147456; int g = e >> 6, c = e & 63;
        wsu[gid] = packh(w_ih2[g * H_ + 2 * c], w_ih2[g * H_ + 2 * c + 1]);
    } else if (gid < 212992) {
        int e = gid - 180224; int g = e >> 6, c = e & 63;
        wsu[gid] = packh(w_hh2[g * H_ + 2 * c], w_hh2[g * H_ + 2 * c + 1]);
    } else if (gid < 215040) {
        int e = gid - 212992; int o = e >> 6, c = e & 63;
        wsu[gid] = packh(wax[o * H_ + 2 * c], wax[o * H_ + 2 * c + 1]);
    } else if (gid < 217216) {
        int e = gid - 215040; int o = e / 68, c = e % 68;
        int col = c < 64 ? 2 * c : 160 + 2 * (c - 64);
        wsu[gid] = packh(wmx[o * MKD + col], wmx[o * MKD + col + 1]);
    } else if (gid < 219392) {
        int e = gid - 217216; int o = e / 68, c = e % 68;
        int col = c < 64 ? 2 * c : 160 + 2 * (c - 64);
        wsu[gid] = packh(wmt[o * MKD + col], wmt[o * MKD + col + 1]);
    } else if (gid < 219904) {
        int e = gid - 219392; int o = e >> 4, c = e & 15;
        wsu[gid] = packh(wat[o * 64 + 2 * c], wat[o * 64 + 2 * c + 1]);
    } else if (gid < 221440) {
        int e = gid - 219904; int layer = e >> 9, g = e & 511;
        float v;
        if (layer == 0)      v = b_ih0[g] + b_hh0[g];
        else if (layer == 1) v = b_ih1[g] + b_hh1[g];
        else                 v = b_ih2[g] + b_hh2[g];
        ((float*)wsu)[gid] = v;
    }
}

// ---------------------------------------------------------------------------
// kT: dt tables (48 x 96): [tmx(+bmx) | tmt(+bmt) | tat(+bat)]
// ---------------------------------------------------------------------------
__global__ void __launch_bounds__(256)
kT(const float* __restrict__ t_emb,
   const float* __restrict__ wmx, const float* __restrict__ wmt,
   const float* __restrict__ wat,
   const float* __restrict__ bmx, const float* __restrict__ bmt,
   const float* __restrict__ bat, float* __restrict__ ttab)
{
    int gid = blockIdx.x * 256 + threadIdx.x;
    if (gid >= 48 * 96) return;
    int dt = gid / 96, o96 = gid % 96;
    const float* te = t_emb + dt * TE;
    int o = o96 & 31;
    float acc;
    const float* w;
    if (o96 < 32)      { acc = bmx[o]; w = wmx + o * MKD + XE; }
    else if (o96 < 64) { acc = bmt[o]; w = wmt + o * MKD + XE; }
    else               { acc = bat[o]; w = wat + o * 64 + TE; }
    for (int d = 0; d < TE; ++d) acc = fmaf(te[d], w[d], acc);
    ttab[dt * 96 + o96] = acc;
}

// ---------------------------------------------------------------------------
// kE: per-edge tables (50000 x 96): [emx | emt | eat]  (no biases)
// ---------------------------------------------------------------------------
__global__ void __launch_bounds__(256)
kE(const float* __restrict__ x_emb, const float* __restrict__ eprop,
   const float* __restrict__ tcost,
   const u32* __restrict__ wmxp, const u32* __restrict__ wmtp,
   const u32* __restrict__ watp0, float* __restrict__ etab)
{
    __shared__ uint4 smx[544], smt[544], sat[128];
    int tid = threadIdx.x;
    for (int i = tid; i < 544; i += 256) {
        smx[i] = ((const uint4*)wmxp)[i];
        smt[i] = ((const uint4*)wmtp)[i];
    }
    if (tid < 128) sat[tid] = ((const uint4*)watp0)[tid];
    __syncthreads();
    int e = blockIdx.x * 256 + tid;
    if (e >= NE) return;

    u32 in[68], tin[16];
    const float* xr = x_emb + (size_t)e * XE;
#pragma unroll
    for (int c = 0; c < 64; ++c) in[c] = packh(xr[2 * c], xr[2 * c + 1]);
    const float* er = eprop + (size_t)e * EP;
#pragma unroll
    for (int c = 0; c < 4; ++c) in[64 + c] = packh(er[2 * c], er[2 * c + 1]);
    const float* tr = tcost + (size_t)e * TE;
#pragma unroll
    for (int c = 0; c < 16; ++c) tin[c] = packh(tr[2 * c], tr[2 * c + 1]);

    float* outp = etab + (size_t)e * 96;
    for (int o = 0; o < OD; ++o) {
        float ax = 0.f, am = 0.f, aa = 0.f;
#pragma unroll
        for (int c4 = 0; c4 < 17; ++c4) {
            uint4 wx = smx[o * 17 + c4], wt = smt[o * 17 + c4];
            ax = dot2f(wx.x, in[c4 * 4 + 0], ax);
            ax = dot2f(wx.y, in[c4 * 4 + 1], ax);
            ax = dot2f(wx.z, in[c4 * 4 + 2], ax);
            ax = dot2f(wx.w, in[c4 * 4 + 3], ax);
            am = dot2f(wt.x, in[c4 * 4 + 0], am);
            am = dot2f(wt.y, in[c4 * 4 + 1], am);
            am = dot2f(wt.z, in[c4 * 4 + 2], am);
            am = dot2f(wt.w, in[c4 * 4 + 3], am);
        }
#pragma unroll
        for (int c4 = 0; c4 < 4; ++c4) {
            uint4 wa = sat[o * 4 + c4];
            aa = dot2f(wa.x, tin[c4 * 4 + 0], aa);
            aa = dot2f(wa.y, tin[c4 * 4 + 1], aa);
            aa = dot2f(wa.z, tin[c4 * 4 + 2], aa);
            aa = dot2f(wa.w, tin[c4 * 4 + 3], aa);
        }
        outp[o] = ax; outp[32 + o] = am; outp[64 + o] = aa;
    }
}

// ---------------------------------------------------------------------------
// kAP: build layer-0 A panel [65536][96 u32] (K=192, pad 184..191 = 0)
// ---------------------------------------------------------------------------
__global__ void __launch_bounds__(512)
kAP(const int* __restrict__ x, const int* __restrict__ dpt,
    const float* __restrict__ z, const float* __restrict__ eprop,
    const float* __restrict__ x_emb, const float* __restrict__ t_emb,
    u32* __restrict__ A0)
{
    int tid = threadIdx.x;
    int i = tid >> 2, q = tid & 3;
    int bl = blockIdx.x * 128 + i;
    int xt = x[bl], dt = dpt[bl];
    int b = bl >> 7, l = bl & 127;
    const float* zr = z + ((size_t)l * B_ + b) * ZD;
    const float* xr = x_emb + (size_t)xt * XE;
    const float* tr = t_emb + (size_t)dt * TE;
    const float* er = eprop + (size_t)xt * EP;
    u32* outp = A0 + (size_t)bl * 96;
#pragma unroll
    for (int cc = 0; cc < 24; ++cc) {
        int c = q * 24 + cc;
        float lo, hi;
        if (c < 8)       { lo = zr[2 * c];          hi = zr[2 * c + 1]; }
        else if (c < 72) { lo = xr[2 * (c - 8)];    hi = xr[2 * (c - 8) + 1]; }
        else if (c < 88) { lo = tr[2 * (c - 72)];   hi = tr[2 * (c - 72) + 1]; }
        else if (c < 92) { lo = er[2 * (c - 88)];   hi = er[2 * (c - 88) + 1]; }
        else             { lo = 0.f;                hi = 0.f; }
        outp[c] = packh(lo, hi);
    }
}

// ---------------------------------------------------------------------------
// kGm<KC>: MFMA GEMM.  Out[M][512] (f16) = A[M][KC*32] @ W[512][KC*32]^T + bsum.
// ---------------------------------------------------------------------------
template<int KC>
__global__ void __launch_bounds__(512, 2)
kGm(const _Float16* __restrict__ A, const u32* __restrict__ Wp,
    const float* __restrict__ bsum, _Float16* __restrict__ Out)
{
    const int K = KC * 32;
    int tid = threadIdx.x;
    int w = tid >> 6, l = tid & 63;
    int lr = l & 15, lq = l >> 4;
    int bl0 = blockIdx.x * 64;

    half8 a[4][KC];
#pragma unroll
    for (int t = 0; t < 4; ++t)
#pragma unroll
        for (int c = 0; c < KC; ++c)
            a[t][c] = *reinterpret_cast<const half8*>(
                A + (size_t)(bl0 + t * 16 + lr) * K + c * 32 + lq * 8);

#pragma unroll
    for (int pass = 0; pass < 4; ++pass) {
        int g = pass * 128 + w * 16 + lr;
        half8 bfr[KC];
#pragma unroll
        for (int c = 0; c < KC; ++c)
            bfr[c] = *reinterpret_cast<const half8*>(
                (const _Float16*)Wp + (size_t)g * K + c * 32 + lq * 8);
        float bias = bsum[g];
#pragma unroll
        for (int t = 0; t < 4; ++t) {
            f32x4 acc = {0.f, 0.f, 0.f, 0.f};
#pragma unroll
            for (int c = 0; c < KC; ++c)
                acc = __builtin_amdgcn_mfma_f32_16x16x32_f16(a[t][c], bfr[c], acc, 0, 0, 0);
#pragma unroll
            for (int j = 0; j < 4; ++j) {
                int item = bl0 + t * 16 + lq * 4 + j;
                Out[(size_t)item * G4 + g] = (_Float16)(acc[j] + bias);
            }
        }
    }
}

// ---------------------------------------------------------------------------
// kLrec: serial LSTM recurrence, one layer.  512 blocks x 256 threads,
// 1 batch row per block, 2 gates per thread; w_hh rows PINNED in VGPRs
// (asm-defined values cannot be rematerialized into per-step L2 re-fetches —
// round-4 profile showed VGPR=80 + 45 TB/s L2 traffic from exactly that).
// ---------------------------------------------------------------------------
__global__ void __launch_bounds__(256, 2)
kLrec(const _Float16* __restrict__ gin, const u32* __restrict__ whp,
      _Float16* __restrict__ hout)
{
    __shared__ u32 sh[64];        // packed f16 h[128]
    __shared__ float sg[G4];
    int t = threadIdx.x;          // 0..255
    int bidx = blockIdx.x;        // batch row

    uint4 wA[16], wB[16];
#pragma unroll
    for (int j4 = 0; j4 < 16; ++j4) {
        wA[j4] = ((const uint4*)whp)[t * 16 + j4];
        wB[j4] = ((const uint4*)whp)[(t + 256) * 16 + j4];
    }
    // Pin in VGPRs: asm-defined -> not rematerializable.
#pragma unroll
    for (int j4 = 0; j4 < 16; ++j4) {
        asm volatile("" : "+v"(wA[j4].x), "+v"(wA[j4].y), "+v"(wA[j4].z), "+v"(wA[j4].w));
        asm volatile("" : "+v"(wB[j4].x), "+v"(wB[j4].y), "+v"(wB[j4].z), "+v"(wB[j4].w));
    }

    if (t < 64) sh[t] = 0;
    float c_reg = 0.f;
    const _Float16* gbase = gin + (size_t)bidx * L_ * G4;
    float gA = (float)gbase[t], gB = (float)gbase[t + 256];
    __syncthreads();

    for (int l = 0; l < L_; ++l) {
        const _Float16* gnext = gbase + (size_t)(l < L_ - 1 ? l + 1 : l) * G4;
        float nA = (float)gnext[t], nB = (float)gnext[t + 256];
        float aA = gA, aB = gB;
        const uint4* shv = (const uint4*)sh;
#pragma unroll
        for (int j4 = 0; j4 < 16; ++j4) {
            uint4 hv = shv[j4];
            aA = dot4(wA[j4], hv, aA);
            aB = dot4(wB[j4], hv, aB);
        }
        sg[t] = aA; sg[t + 256] = aB;
        __syncthreads();
        if (t < 128) {
            float gi = sg[t], gf = sg[H_ + t], gg = sg[2 * H_ + t], go = sg[3 * H_ + t];
            float c = sigm(gf) * c_reg + sigm(gi) * tanh_f(gg);
            float h = sigm(go) * tanh_f(c);
            c_reg = c;
            _Float16 hh = (_Float16)h;
            ((_Float16*)sh)[t] = hh;
            hout[((size_t)bidx * L_ + l) * H_ + t] = hh;
        }
        __syncthreads();
        gA = nA; gB = nB;
    }
}

// ---------------------------------------------------------------------------
// kX2: fused epilogue.  afterx from h2 (f16 dot2), px/pt from etab+ttab.
// ---------------------------------------------------------------------------
__global__ void __launch_bounds__(256)
kX2(const int* __restrict__ x, const int* __restrict__ dpt,
    const int* __restrict__ adj, const __half* __restrict__ h2seq,
    const u32* __restrict__ wap, const float* __restrict__ bax,
    const float* __restrict__ etab, const float* __restrict__ ttab,
    float* __restrict__ pred_x, float* __restrict__ pred_t)
{
    __shared__ uint4 swp[512];
    __shared__ float stt[48 * 96];
    __shared__ float sbax[32];
    int tid = threadIdx.x;
    for (int i = tid; i < 512; i += 256) swp[i] = ((const uint4*)wap)[i];
    for (int i = tid; i < 4608; i += 256) stt[i] = ttab[i];
    if (tid < 32) sbax[tid] = bax[tid];
    __syncthreads();

    int bl = blockIdx.x * 256 + tid;
    int xt = x[bl], dt = dpt[bl];

    uint4 h2r[16];
    const uint4* h2p = (const uint4*)(h2seq + (size_t)bl * H_);
#pragma unroll
    for (int q = 0; q < 16; ++q) h2r[q] = h2p[q];

    float afterx[OD];
    for (int o = 0; o < OD; ++o) {
        float acc = sbax[o];
#pragma unroll
        for (int q = 0; q < 16; ++q) {
            uint4 w = swp[o * 16 + q];
            acc = dot2f(w.x, h2r[q].x, acc);
            acc = dot2f(w.y, h2r[q].y, acc);
            acc = dot2f(w.z, h2r[q].z, acc);
            acc = dot2f(w.w, h2r[q].w, acc);
        }
        afterx[o] = acc > 0.f ? acc : 0.f;
    }

    const float4* tp = (const float4*)(stt + dt * 96);
    float px[K_];
#pragma unroll
    for (int k = 0; k < K_; ++k) {
        int a = adj[xt * K_ + k];
        int ac = a < NE ? a : 0;
        const float4* ep = (const float4*)(etab + (size_t)ac * 96);
        float sx = 0.f, st = 0.f;
#pragma unroll
        for (int q = 0; q < 8; ++q) {
            float4 e = ep[q], tt = tp[q];
            sx += afterx[q * 4 + 0] * (e.x + tt.x)
                + afterx[q * 4 + 1] * (e.y + tt.y)
                + afterx[q * 4 + 2] * (e.z + tt.z)
                + afterx[q * 4 + 3] * (e.w + tt.w);
        }
#pragma unroll
        for (int q = 0; q < 8; ++q) {
            float4 em = ep[8 + q], tm = tp[8 + q];
            float4 ea = ep[16 + q], ta = tp[16 + q];
            float at0 = fmaxf(ea.x + ta.x, 0.f);
            float at1 = fmaxf(ea.y + ta.y, 0.f);
            float at2 = fmaxf(ea.z + ta.z, 0.f);
            float at3 = fmaxf(ea.w + ta.w, 0.f);
            st += at0 * (em.x + tm.x) + at1 * (em.y + tm.y)
                + at2 * (em.z + tm.z) + at3 * (em.w + tm.w);
        }
        px[k] = (a == NE) ? -INFINITY : sx;
        pred_t[(size_t)bl * K_ + k] = 1.f / (1.f + expf(-st));
    }

    float m = px[0];
#pragma unroll
    for (int k = 1; k < K_; ++k) m = fmaxf(m, px[k]);
    float ssum = 0.f;
#pragma unroll
    for (int k = 0; k < K_; ++k) ssum += expf(px[k] - m);
    float lse = logf(ssum) + m;
#pragma unroll
    for (int k = 0; k < K_; ++k)
        pred_x[(size_t)bl * K_ + k] = px[k] - lse;
}

// ---------------------------------------------------------------------------
extern "C" void kernel_launch(void* const* d_in, const int* in_sizes, int n_in,
                              void* d_out, int out_size, void* d_ws, size_t ws_size,
                              hipStream_t stream)
{
    (void)in_sizes; (void)n_in; (void)out_size; (void)ws_size;

    const int*   x      = (const int*)  d_in[0];
    const int*   dpt    = (const int*)  d_in[1];
    const float* z      = (const float*)d_in[2];
    const int*   adj    = (const int*)  d_in[3];
    const float* eprop  = (const float*)d_in[4];
    const float* x_emb  = (const float*)d_in[5];
    const float* t_emb  = (const float*)d_in[6];
    const float* tcost  = (const float*)d_in[7];
    const float* w_ih0  = (const float*)d_in[8];
    const float* w_hh0  = (const float*)d_in[9];
    const float* b_ih0  = (const float*)d_in[10];
    const float* b_hh0  = (const float*)d_in[11];
    const float* w_ih1  = (const float*)d_in[12];
    const float* w_hh1  = (const float*)d_in[13];
    const float* b_ih1  = (const float*)d_in[14];
    const float* b_hh1  = (const float*)d_in[15];
    const float* w_ih2  = (const float*)d_in[16];
    const float* w_hh2  = (const float*)d_in[17];
    const float* b_ih2  = (const float*)d_in[18];
    const float* b_hh2  = (const float*)d_in[19];
    const float* wax    = (const float*)d_in[20];
    const float* bax    = (const float*)d_in[21];
    const float* wat    = (const float*)d_in[22];
    const float* bat    = (const float*)d_in[23];
    const float* wmx    = (const float*)d_in[24];
    const float* bmx    = (const float*)d_in[25];
    const float* wmt    = (const float*)d_in[26];
    const float* bmt    = (const float*)d_in[27];

    float* out    = (float*)d_out;
    float* pred_x = out;
    float* pred_t = out + (size_t)B_ * L_ * K_;

    u32* wsu = (u32*)d_ws;
    u32* wih0p = wsu;                 // 49152
    u32* whp0  = wsu + 49152;
    u32* wih1p = wsu + 81920;
    u32* whp1  = wsu + 114688;
    u32* wih2p = wsu + 147456;
    u32* whp2  = wsu + 180224;
    u32* wap   = wsu + 212992;
    u32* wmxp  = wsu + 215040;
    u32* wmtp  = wsu + 217216;
    u32* watp0 = wsu + 219392;
    float* bsum = (float*)(wsu + 219904);          // [3][512]
    u32* A0    = wsu + 221440;                      // 65536*96
    _Float16* gin   = (_Float16*)(wsu + 6512896);   // 65536*512 f16
    _Float16* h0seq = (_Float16*)(wsu + 23290112);  // 65536*128 f16
    _Float16* h1seq = (_Float16*)(wsu + 27484416);
    _Float16* h2seq = (_Float16*)(wsu + 31678720);
    float* etab = (float*)(wsu + 35873024);         // 50000*96
    float* ttab = (float*)(wsu + 40673024);         // 4608

    kW2<<<865, 256, 0, stream>>>(w_ih0, w_hh0, w_ih1, w_hh1, w_ih2, w_hh2,
                                 wax, wmx, wmt, wat,
                                 b_ih0, b_hh0, b_ih1, b_hh1, b_ih2, b_hh2, wsu);

    kT<<<18, 256, 0, stream>>>(t_emb, wmx, wmt, wat, bmx, bmt, bat, ttab);

    kE<<<196, 256, 0, stream>>>(x_emb, eprop, tcost, wmxp, wmtp, watp0, etab);

    kAP<<<512, 512, 0, stream>>>(x, dpt, z, eprop, x_emb, t_emb, A0);

    kGm<6><<<1024, 512, 0, stream>>>((const _Float16*)A0, wih0p, bsum + 0, gin);
    kLrec<<<512, 256, 0, stream>>>(gin, whp0, h0seq);

    kGm<4><<<1024, 512, 0, stream>>>(h0seq, wih1p, bsum + 512, gin);
    kLrec<<<512, 256, 0, stream>>>(gin, whp1, h1seq);

    kGm<4><<<1024, 512, 0, stream>>>(h1seq, wih2p, bsum + 1024, gin);
    kLrec<<<512, 256, 0, stream>>>(gin, whp2, h2seq);

    kX2<<<256, 256, 0, stream>>>(x, dpt, adj, (const __half*)h2seq, wap, bax,
                                 etab, ttab, pred_x, pred_t);
}